// Round 3
// baseline (124.660 us; speedup 1.0000x reference)
//
#include <hip/hip_runtime.h>
#include <stdint.h>

#define T_STEPS  1000
#define BATCH    32
#define N_NEURON 1000
#define IN_DIM   128
#define OUT_DIM  20

typedef unsigned short ushort_t;
typedef unsigned long long ull_t;
using f32x4  = __attribute__((ext_vector_type(4))) float;
using bf16x8 = __attribute__((ext_vector_type(8))) short;

// ws layout (bytes): 250 per-block maxima, ALL rewritten every launch
// (no memset node; gate only reads slots 0..249).
#define OFF_GMAXA 0ull
#define GMAXA_N   250
#define WS_NEED   (GMAXA_N * 4ull)

// Spike needs w >= 15. bf16 truncation-GEMM error bound ~0.15; actual max ~5.5.
// Silence declared iff bf16max < 14.5  =>  exact max < 14.65 < 15. Sound.
#define SIL_TH 14.5f

// Pack two f32 -> one u32 of two bf16 (TRUNCATION, 1 VALU op via v_perm_b32).
// D = { hi16(b), hi16(a) }:  sel 0x07060302 picks a.byte2,a.byte3,b.byte2,b.byte3.
static __device__ __forceinline__ unsigned pack_bf16_trunc(float a, float b) {
    return __builtin_amdgcn_perm(__float_as_uint(b), __float_as_uint(a), 0x07060302u);
}

// ============================================================================
// Kernel 1: max-reduced bf16 MFMA GEMM — one plain store per block.
// Silence proof: w_t = a_v*w_{t-1} + (1-a_v)*I_t (w = v-V_RESET, w0=0) is a
// convex combination of {0, past I}: w_max <= max(0, max I). Spike <=> w>=15.
// gmax < 14.5 => no spike ever, any batch => out = b_out exactly.
//
// v9 (this round): r14 post-mortem — __launch_bounds__(1024, 4) was applied
// with CUDA min-BLOCKS-per-CU semantics: 4 blocks x 16 waves clamped to the
// 32-wave/CU cap -> 8 waves/SIMD -> VGPR cap 512/8 = 64 (counter showed
// VGPR_Count=64), forcing ~70 dwords/thread scratch spill: WRITE_SIZE 72 MB,
// FETCH 81 MB, maxgemm 52-66 us, MfmaUtil 5.5%. Live set is ~85-90 VGPRs.
// Fix: (1024, 1) -> VGPR cap >= 128 under either semantics, no spill.
// Hardware occupancy then lands at the r14 INTENT: ~90 VGPR + 34 KB LDS =>
// 1 block/CU => 16 waves = 4 waves/SIMD TLP (2x round 1) to hide the ~200cy
// L2 latency of the W fragment loads. Traffic unchanged: x fetched exactly
// once (16.4 MB HBM), W 512 KB L2-resident (250 x 512 KB = 128 MB L2,
// ~3.7 us BW floor at 135 GB/s/CU).
// ============================================================================
__global__ __launch_bounds__(1024, 1) void maxgemm_kernel(
    const float* __restrict__ x, const float* __restrict__ W,
    const float* __restrict__ in_scale_p, float* __restrict__ gmaxa)
{
    __shared__ ushort_t xs[128 * 132];   // 33792 B, stride 132 shorts (2-way = free)
    __shared__ float wred[16];
    const int tid  = threadIdx.x;
    const int lane = tid & 63;
    const int wave = tid >> 6;           // 0..15
    const int quad = lane >> 4;
    const int l15  = lane & 15;
    const int m0   = blockIdx.x * 128;   // 250 * 128 = 32000 rows exactly
    const int nwbase = wave * 64;        // wave's 64 padded neurons
    const float is = in_scale_p[0];

    // ---- stage x*is -> bf16 LDS (coalesced; perm-packed; uint2 stores) ----
#pragma unroll
    for (int it = 0; it < 4; ++it) {
        int idx = tid + it * 1024;       // 0..4095 = 128 rows x 32 float4
        int row = idx >> 5, c4 = idx & 31;
        float4 v = *(const float4*)(x + (size_t)(m0 + row) * IN_DIM + c4 * 4);
        v.x *= is; v.y *= is; v.z *= is; v.w *= is;
        unsigned p0 = pack_bf16_trunc(v.x, v.y);
        unsigned p1 = pack_bf16_trunc(v.z, v.w);
        // byte offset row*264 + c4*8 is 8-aligned (264 % 8 == 0)
        *(uint2*)(xs + row * 132 + c4 * 4) = make_uint2(p0, p1);
    }
    __syncthreads();

    float mx = 0.f;    // clamped >= 0 (bound uses max(0, I))

#pragma unroll 1
    for (int pp = 0; pp < 2; ++pp) {     // 2 pairs of 16-neuron tiles
        // ---- B-pair: fp32 W (L2-resident) -> bf16 regs via perm-pack ----
        bf16x8 Bf[2][4];
#pragma unroll
        for (int p = 0; p < 2; ++p) {
            const int row = nwbase + pp * 32 + p * 16 + l15;   // <= 1023
            const bool ok = row < N_NEURON;
            const float* wp = W + (size_t)row * IN_DIM;
#pragma unroll
            for (int kb = 0; kb < 4; ++kb) {
                float4 lo = ok ? *(const float4*)(wp + kb * 32 + quad * 8)
                               : make_float4(0.f, 0.f, 0.f, 0.f);
                float4 hi = ok ? *(const float4*)(wp + kb * 32 + quad * 8 + 4)
                               : make_float4(0.f, 0.f, 0.f, 0.f);
                union { bf16x8 h; uint4 u; } cvt;
                cvt.u = make_uint4(pack_bf16_trunc(lo.x, lo.y),
                                   pack_bf16_trunc(lo.z, lo.w),
                                   pack_bf16_trunc(hi.x, hi.y),
                                   pack_bf16_trunc(hi.z, hi.w));
                Bf[p][kb] = cvt.h;
            }
        }

        // ---- 8 m-tiles x (2 n-tiles x 4 k-blocks) MFMAs -> max ----
#pragma unroll
        for (int mt = 0; mt < 8; ++mt) {
            bf16x8 Af[4];
#pragma unroll
            for (int kb = 0; kb < 4; ++kb)
                Af[kb] = *(const bf16x8*)(xs + (mt * 16 + l15) * 132 +
                                          kb * 32 + quad * 8);
            f32x4 a0 = (f32x4){0.f, 0.f, 0.f, 0.f};
            f32x4 a1 = (f32x4){0.f, 0.f, 0.f, 0.f};
#pragma unroll
            for (int kb = 0; kb < 4; ++kb) {
                a0 = __builtin_amdgcn_mfma_f32_16x16x32_bf16(Af[kb], Bf[0][kb], a0, 0, 0, 0);
                a1 = __builtin_amdgcn_mfma_f32_16x16x32_bf16(Af[kb], Bf[1][kb], a1, 0, 0, 0);
            }
#pragma unroll
            for (int i = 0; i < 4; ++i) {
                mx = fmaxf(mx, a0[i]);
                mx = fmaxf(mx, a1[i]);
            }
        }
    }

    // ---- lanes -> wave -> block (LDS) -> ONE plain store, no atomics ----
#pragma unroll
    for (int off = 32; off > 0; off >>= 1)
        mx = fmaxf(mx, __shfl_xor(mx, off, 64));
    if (lane == 0) wred[wave] = mx;
    __syncthreads();
    if (tid == 0) {
        float bm = wred[0];
#pragma unroll
        for (int i = 1; i < 16; ++i) bm = fmaxf(bm, wred[i]);
        gmaxa[blockIdx.x] = bm;          // slots 0..249, all written
    }
}

// ============================================================================
// Kernel 2: gated full sequential sim (round-1 structure, known correct),
// with the resolve folded in: each block scans the 250 per-block maxima
// (bounds-checked -> never reads unwritten/poisoned slots); if silence is
// proven, write out = b_out bitwise and exit. gmaxa == nullptr -> always run.
// ============================================================================
__global__ __launch_bounds__(256) void rsnn_seq_kernel(
    const float* __restrict__ gmaxa,
    const float* __restrict__ x,
    const float* __restrict__ W_in,
    const float* __restrict__ W_rec,
    const float* __restrict__ asc_amps,
    const float* __restrict__ k_decay,
    const float* __restrict__ W_out,
    const float* __restrict__ b_out,
    const float* __restrict__ in_scale_p,
    const float* __restrict__ out_scale_p,
    float* __restrict__ out)
{
    const int b   = blockIdx.x;
    const int tid = threadIdx.x;

    if (gmaxa) {
        bool trig = (tid < GMAXA_N) && (gmaxa[tid] >= SIL_TH);
        int any = __syncthreads_or(trig ? 1 : 0);   // block-uniform
        if (any == 0) {                             // silence proven
            if (tid < OUT_DIM) out[b * OUT_DIM + tid] = b_out[tid];
            return;
        }
    }

    const int lane = tid & 63;
    const int wave = tid >> 6;
    const bool active = tid < (N_NEURON / 4);
    const int n0 = tid * 4;

    __shared__ ull_t smask[2][16];
    __shared__ float acc_sh[N_NEURON];
    __shared__ float xr[2][IN_DIM];

    const float a_v      = expf(-1.0f / 20.0f);
    const float a_syn    = expf(-1.0f / 5.0f);
    const float a_read   = expf(-1.0f / 20.0f);
    const float one_m_av = 1.0f - a_v;
    const float one_m_ar = 1.0f - a_read;
    const float VR = -60.0f, VTH = -45.0f;
    const float in_scale  = in_scale_p[0];
    const float out_scale = out_scale_p[0];

    float v[4], Ia[4], psc[4], f[4], acc[4], aasc[4], amp[4];
#pragma unroll
    for (int c = 0; c < 4; ++c) {
        v[c] = VR; Ia[c] = 0.f; psc[c] = 0.f; f[c] = 0.f; acc[c] = 0.f;
        aasc[c] = active ? expf(-k_decay[n0 + c]) : 0.f;
        amp[c]  = active ? asc_amps[n0 + c] : 0.f;
    }
    if (tid < 16) { smask[0][tid] = 0ull; smask[1][tid] = 0ull; }

    if (tid < IN_DIM / 4) {
        float4 xv = ((const float4*)(x + (size_t)b * IN_DIM))[tid];
        xr[0][tid * 4 + 0] = xv.x * in_scale; xr[0][tid * 4 + 1] = xv.y * in_scale;
        xr[0][tid * 4 + 2] = xv.z * in_scale; xr[0][tid * 4 + 3] = xv.w * in_scale;
    }
    int prev_any = 0;
    __syncthreads();

    for (int t = 0; t < T_STEPS; ++t) {
        const int cur = t & 1, nxt = cur ^ 1;
        if (t + 1 < T_STEPS && tid < IN_DIM / 4) {
            float4 xv = ((const float4*)(x + (size_t)((t + 1) * BATCH + b) * IN_DIM))[tid];
            xr[nxt][tid * 4 + 0] = xv.x * in_scale; xr[nxt][tid * 4 + 1] = xv.y * in_scale;
            xr[nxt][tid * 4 + 2] = xv.z * in_scale; xr[nxt][tid * 4 + 3] = xv.w * in_scale;
        }
        float4 Icur = make_float4(0.f, 0.f, 0.f, 0.f);
        if (active) {
            float s0 = 0.f, s1 = 0.f, s2 = 0.f, s3 = 0.f;
            const float4* w0 = (const float4*)(W_in + (size_t)(n0 + 0) * IN_DIM);
            const float4* w1 = (const float4*)(W_in + (size_t)(n0 + 1) * IN_DIM);
            const float4* w2 = (const float4*)(W_in + (size_t)(n0 + 2) * IN_DIM);
            const float4* w3 = (const float4*)(W_in + (size_t)(n0 + 3) * IN_DIM);
#pragma unroll 8
            for (int k4 = 0; k4 < IN_DIM / 4; ++k4) {
                float4 xv = *((const float4*)&xr[cur][0] + k4);
                float4 a0 = w0[k4], a1 = w1[k4], a2 = w2[k4], a3 = w3[k4];
                s0 += xv.x * a0.x + xv.y * a0.y + xv.z * a0.z + xv.w * a0.w;
                s1 += xv.x * a1.x + xv.y * a1.y + xv.z * a1.z + xv.w * a1.w;
                s2 += xv.x * a2.x + xv.y * a2.y + xv.z * a2.z + xv.w * a2.w;
                s3 += xv.x * a3.x + xv.y * a3.y + xv.z * a3.z + xv.w * a3.w;
            }
            Icur = make_float4(s0, s1, s2, s3);
        }

#pragma unroll
        for (int c = 0; c < 4; ++c) psc[c] *= a_syn;
        if (prev_any && active) {
#pragma unroll 1
            for (int w = 0; w < 16; ++w) {
                ull_t m = smask[nxt][w];
                while (m) {
                    int bit = __ffsll(m) - 1;
                    m &= m - 1;
                    int npre = ((w >> 2) << 8) + (bit << 2) + (w & 3);
                    const float4 wr = *(const float4*)(W_rec + (size_t)npre * N_NEURON + n0);
                    psc[0] += wr.x; psc[1] += wr.y; psc[2] += wr.z; psc[3] += wr.w;
                }
            }
        }

        float Iv[4] = {Icur.x, Icur.y, Icur.z, Icur.w};
        bool sp[4];
#pragma unroll
        for (int c = 0; c < 4; ++c) {
            float It = Iv[c] + psc[c] + Ia[c];
            float vn = VR + a_v * (v[c] - VR) + one_m_av * It;
            bool s = active && (vn - VTH >= 0.0f);
            float sf = s ? 1.0f : 0.0f;
            vn = vn - (vn - VR) * sf;
            v[c] = vn;
            Ia[c] = aasc[c] * Ia[c] + amp[c] * sf;
            f[c] = (t == 0) ? sf : (a_read * f[c] + one_m_ar * sf);
            if (t >= 199) acc[c] += f[c];
            sp[c] = s;
        }

#pragma unroll
        for (int c = 0; c < 4; ++c) {
            ull_t m = __ballot(sp[c]);
            if (lane == 0) smask[cur][wave * 4 + c] = m;
        }
        int myany = (sp[0] | sp[1] | sp[2] | sp[3]) ? 1 : 0;
        prev_any = __syncthreads_or(myany);
    }

    if (active) {
        acc_sh[n0 + 0] = acc[0]; acc_sh[n0 + 1] = acc[1];
        acc_sh[n0 + 2] = acc[2]; acc_sh[n0 + 3] = acc[3];
    }
    __syncthreads();

    const float inv_cnt = 1.0f / 801.0f;
#pragma unroll
    for (int oo = 0; oo < 5; ++oo) {
        int o = wave * 5 + oo;
        float p = 0.f;
        for (int n = lane; n < N_NEURON; n += 64)
            p += acc_sh[n] * W_out[(size_t)o * N_NEURON + n];
#pragma unroll
        for (int off = 32; off > 0; off >>= 1)
            p += __shfl_down(p, off, 64);
        if (lane == 0)
            out[b * OUT_DIM + o] = out_scale * (p * inv_cnt) + b_out[o];
    }
}

// ============================================================================
extern "C" void kernel_launch(void* const* d_in, const int* in_sizes, int n_in,
                              void* d_out, int out_size, void* d_ws, size_t ws_size,
                              hipStream_t stream)
{
    const float* x         = (const float*)d_in[0];
    const float* W_in      = (const float*)d_in[1];
    const float* W_rec     = (const float*)d_in[2];
    const float* asc_amps  = (const float*)d_in[3];
    const float* k_decay   = (const float*)d_in[4];
    const float* W_out     = (const float*)d_in[5];
    const float* b_out     = (const float*)d_in[6];
    const float* in_scale  = (const float*)d_in[7];
    const float* out_scale = (const float*)d_in[8];
    float* out = (float*)d_out;

    if (ws_size >= WS_NEED) {
        float* gmaxa = (float*)((char*)d_ws + OFF_GMAXA);
        maxgemm_kernel<<<250, 1024, 0, stream>>>(x, W_in, in_scale, gmaxa);
        rsnn_seq_kernel<<<BATCH, 256, 0, stream>>>(
            gmaxa, x, W_in, W_rec, asc_amps, k_decay, W_out, b_out,
            in_scale, out_scale, out);
    } else {
        rsnn_seq_kernel<<<BATCH, 256, 0, stream>>>(
            nullptr, x, W_in, W_rec, asc_amps, k_decay, W_out, b_out,
            in_scale, out_scale, out);
    }
}

// Round 4
// 88.773 us; speedup vs baseline: 1.4042x; 1.4042x over previous
//
#include <hip/hip_runtime.h>
#include <stdint.h>

#define T_STEPS  1000
#define BATCH    32
#define N_NEURON 1000
#define IN_DIM   128
#define OUT_DIM  20

typedef unsigned short ushort_t;
typedef unsigned long long ull_t;
using f32x4  = __attribute__((ext_vector_type(4))) float;
using bf16x8 = __attribute__((ext_vector_type(8))) short;

// ws layout (bytes):
//   [0, 2000)        : 500 per-block maxima (ALL rewritten every launch)
//   [4096, 4096+256K): W in bf16, MFMA-fragment order (ALL rewritten every launch)
#define OFF_GMAXA 0ull
#define GMAXA_N   500
#define OFF_WB    4096ull
#define WB_BYTES  (1024ull * 128ull * 2ull)     // 256 KB
#define WS_NEED   (OFF_WB + WB_BYTES)

// Spike needs w >= 15. bf16 truncation-GEMM error bound ~0.15; actual max ~5.5.
// Silence declared iff bf16max < 14.5  =>  exact max < 14.65 < 15. Sound.
#define SIL_TH 14.5f

// Pack two f32 -> one u32 of two bf16 (TRUNCATION, 1 VALU op via v_perm_b32).
// D = { hi16(b), hi16(a) }:  sel 0x07060302 picks a.byte2,a.byte3,b.byte2,b.byte3.
static __device__ __forceinline__ unsigned pack_bf16_trunc(float a, float b) {
    return __builtin_amdgcn_perm(__float_as_uint(b), __float_as_uint(a), 0x07060302u);
}

// ============================================================================
// Kernel 0: W fp32 -> bf16, MFMA-FRAGMENT order, padded rows zeroed.
// Fragment layout: for (ntile 0..63, kb 0..3, lane 0..63) the 16 B at
//   Wb + ((ntile*4 + kb)*64 + lane)*8 shorts
// hold W[ntile*16 + (lane&15)][kb*32 + (lane>>4)*8 + 0..7] — i.e. exactly the
// bf16x8 B-operand lane `lane` needs for n-tile `ntile`, k-block `kb`. A
// wave's B-load is then ONE contiguous 1 KB global_load_dwordx4. Rows >= 1000
// are written as zeros (their MFMA contribution vanishes; no branches later).
// 16384 threads x 16 B = 256 KB, every byte of the ws region written.
// ============================================================================
__global__ __launch_bounds__(256) void wconv_kernel(
    const float* __restrict__ W, ushort_t* __restrict__ Wb)
{
    const int i    = blockIdx.x * 256 + threadIdx.x;  // 0..16383, one uint4 each
    const int lane = i & 63;
    const int kb   = (i >> 6) & 3;
    const int nt   = i >> 8;                          // 0..63
    const int row  = nt * 16 + (lane & 15);
    const int k0   = kb * 32 + (lane >> 4) * 8;
    uint4 o;
    if (row < N_NEURON) {
        const float* wp = W + (size_t)row * IN_DIM + k0;
        float4 lo = *(const float4*)(wp);
        float4 hi = *(const float4*)(wp + 4);
        o = make_uint4(pack_bf16_trunc(lo.x, lo.y), pack_bf16_trunc(lo.z, lo.w),
                       pack_bf16_trunc(hi.x, hi.y), pack_bf16_trunc(hi.z, hi.w));
    } else {
        o = make_uint4(0u, 0u, 0u, 0u);
    }
    *(uint4*)(Wb + (size_t)i * 8) = o;
}

// ============================================================================
// Kernel 1: max-reduced bf16 MFMA GEMM — one plain store per block.
// Silence proof: w_t = a_v*w_{t-1} + (1-a_v)*I_t (w = v-V_RESET, w0=0) is a
// convex combination of {0, past I}: w_max <= max(0, max I). Spike <=> w>=15.
// gmax < 14.5 => no spike ever, any batch => out = b_out exactly.
//
// v10: r15/r16 post-mortem — 1024-thr workgroups get a hard 64-VGPR budget on
// this toolchain regardless of __launch_bounds__ ((1024,4) and (1024,1) both
// compiled to VGPR_Count=64, 72 MB scratch writes, 52 µs). Abandon 1024-thr.
// Back to the r13-proven 512-thr register shape (live ~70 VGPR, no spill),
// with the two real bottlenecks fixed instead:
//   * B-loads: preconverted bf16 fragment-ordered W (wconv) — one contiguous
//     1 KB dwordx4 per (p,kb) instead of 32 scattered float4 + 16 perm-packs.
//     Halves B L2 bytes, removes ALL conversion VALU from the hot loop.
//   * TLP: grid 500 x 64-row tiles -> 2 blocks/CU (LDS 16.9 KB, VGPR < 128)
//     = 4 waves/SIMD to hide L2 latency. x still fetched exactly once
//     (500 x 32 KB = 16.4 MB HBM, ~2.6 µs floor).
// ============================================================================
__global__ __launch_bounds__(512, 2) void maxgemm_kernel(
    const float* __restrict__ x, const ushort_t* __restrict__ Wb,
    const float* __restrict__ in_scale_p, float* __restrict__ gmaxa)
{
    __shared__ ushort_t xs[64 * 132];    // 16896 B, stride 132 shorts (2-way = free)
    __shared__ float wred[8];
    const int tid  = threadIdx.x;
    const int lane = tid & 63;
    const int wave = tid >> 6;           // 0..7
    const int quad = lane >> 4;
    const int l15  = lane & 15;
    const int m0   = blockIdx.x * 64;    // 500 * 64 = 32000 rows exactly
    const float is = in_scale_p[0];

    // ---- stage x*is -> bf16 LDS (coalesced; perm-packed; uint2 stores) ----
#pragma unroll
    for (int it = 0; it < 4; ++it) {
        int idx = tid + it * 512;        // 0..2047 = 64 rows x 32 float4
        int row = idx >> 5, c4 = idx & 31;
        float4 v = *(const float4*)(x + (size_t)(m0 + row) * IN_DIM + c4 * 4);
        v.x *= is; v.y *= is; v.z *= is; v.w *= is;
        unsigned p0 = pack_bf16_trunc(v.x, v.y);
        unsigned p1 = pack_bf16_trunc(v.z, v.w);
        // byte offset row*264 + c4*8 is 8-aligned (264 % 8 == 0)
        *(uint2*)(xs + row * 132 + c4 * 4) = make_uint2(p0, p1);
    }
    __syncthreads();

    float mx = 0.f;    // clamped >= 0 (bound uses max(0, I))

    // wave owns n-tiles [wave*8, wave*8+8), processed as 4 pairs
#pragma unroll 1
    for (int pp = 0; pp < 4; ++pp) {
        // ---- B-pair: fragment-ordered bf16 W, one dwordx4 per (p,kb) ----
        bf16x8 Bf[2][4];
#pragma unroll
        for (int p = 0; p < 2; ++p) {
            const int nt = wave * 8 + pp * 2 + p;       // 0..63
#pragma unroll
            for (int kb = 0; kb < 4; ++kb)
                Bf[p][kb] = *(const bf16x8*)(Wb + ((size_t)(nt * 4 + kb) * 64 + lane) * 8);
        }

        // ---- 4 m-tiles x (2 n-tiles x 4 k-blocks) MFMAs -> max ----
#pragma unroll
        for (int mt = 0; mt < 4; ++mt) {
            bf16x8 Af[4];
#pragma unroll
            for (int kb = 0; kb < 4; ++kb)
                Af[kb] = *(const bf16x8*)(xs + (mt * 16 + l15) * 132 +
                                          kb * 32 + quad * 8);
            f32x4 a0 = (f32x4){0.f, 0.f, 0.f, 0.f};
            f32x4 a1 = (f32x4){0.f, 0.f, 0.f, 0.f};
#pragma unroll
            for (int kb = 0; kb < 4; ++kb) {
                a0 = __builtin_amdgcn_mfma_f32_16x16x32_bf16(Af[kb], Bf[0][kb], a0, 0, 0, 0);
                a1 = __builtin_amdgcn_mfma_f32_16x16x32_bf16(Af[kb], Bf[1][kb], a1, 0, 0, 0);
            }
#pragma unroll
            for (int i = 0; i < 4; ++i) {
                mx = fmaxf(mx, a0[i]);
                mx = fmaxf(mx, a1[i]);
            }
        }
    }

    // ---- lanes -> wave -> block (LDS) -> ONE plain store, no atomics ----
#pragma unroll
    for (int off = 32; off > 0; off >>= 1)
        mx = fmaxf(mx, __shfl_xor(mx, off, 64));
    if (lane == 0) wred[wave] = mx;
    __syncthreads();
    if (tid == 0) {
        float bm = wred[0];
#pragma unroll
        for (int i = 1; i < 8; ++i) bm = fmaxf(bm, wred[i]);
        gmaxa[blockIdx.x] = bm;          // slots 0..499, all written
    }
}

// ============================================================================
// Kernel 2: gated full sequential sim (round-1 structure, known correct),
// with the resolve folded in: each block scans the 500 per-block maxima
// (strided; all slots freshly written -> never reads poisoned data); if
// silence is proven, write out = b_out bitwise and exit. gmaxa == nullptr ->
// always run.
// ============================================================================
__global__ __launch_bounds__(256) void rsnn_seq_kernel(
    const float* __restrict__ gmaxa,
    const float* __restrict__ x,
    const float* __restrict__ W_in,
    const float* __restrict__ W_rec,
    const float* __restrict__ asc_amps,
    const float* __restrict__ k_decay,
    const float* __restrict__ W_out,
    const float* __restrict__ b_out,
    const float* __restrict__ in_scale_p,
    const float* __restrict__ out_scale_p,
    float* __restrict__ out)
{
    const int b   = blockIdx.x;
    const int tid = threadIdx.x;

    if (gmaxa) {
        bool trig = false;
        for (int i = tid; i < GMAXA_N; i += 256)
            trig |= (gmaxa[i] >= SIL_TH);
        int any = __syncthreads_or(trig ? 1 : 0);   // block-uniform
        if (any == 0) {                             // silence proven
            if (tid < OUT_DIM) out[b * OUT_DIM + tid] = b_out[tid];
            return;
        }
    }

    const int lane = tid & 63;
    const int wave = tid >> 6;
    const bool active = tid < (N_NEURON / 4);
    const int n0 = tid * 4;

    __shared__ ull_t smask[2][16];
    __shared__ float acc_sh[N_NEURON];
    __shared__ float xr[2][IN_DIM];

    const float a_v      = expf(-1.0f / 20.0f);
    const float a_syn    = expf(-1.0f / 5.0f);
    const float a_read   = expf(-1.0f / 20.0f);
    const float one_m_av = 1.0f - a_v;
    const float one_m_ar = 1.0f - a_read;
    const float VR = -60.0f, VTH = -45.0f;
    const float in_scale  = in_scale_p[0];
    const float out_scale = out_scale_p[0];

    float v[4], Ia[4], psc[4], f[4], acc[4], aasc[4], amp[4];
#pragma unroll
    for (int c = 0; c < 4; ++c) {
        v[c] = VR; Ia[c] = 0.f; psc[c] = 0.f; f[c] = 0.f; acc[c] = 0.f;
        aasc[c] = active ? expf(-k_decay[n0 + c]) : 0.f;
        amp[c]  = active ? asc_amps[n0 + c] : 0.f;
    }
    if (tid < 16) { smask[0][tid] = 0ull; smask[1][tid] = 0ull; }

    if (tid < IN_DIM / 4) {
        float4 xv = ((const float4*)(x + (size_t)b * IN_DIM))[tid];
        xr[0][tid * 4 + 0] = xv.x * in_scale; xr[0][tid * 4 + 1] = xv.y * in_scale;
        xr[0][tid * 4 + 2] = xv.z * in_scale; xr[0][tid * 4 + 3] = xv.w * in_scale;
    }
    int prev_any = 0;
    __syncthreads();

    for (int t = 0; t < T_STEPS; ++t) {
        const int cur = t & 1, nxt = cur ^ 1;
        if (t + 1 < T_STEPS && tid < IN_DIM / 4) {
            float4 xv = ((const float4*)(x + (size_t)((t + 1) * BATCH + b) * IN_DIM))[tid];
            xr[nxt][tid * 4 + 0] = xv.x * in_scale; xr[nxt][tid * 4 + 1] = xv.y * in_scale;
            xr[nxt][tid * 4 + 2] = xv.z * in_scale; xr[nxt][tid * 4 + 3] = xv.w * in_scale;
        }
        float4 Icur = make_float4(0.f, 0.f, 0.f, 0.f);
        if (active) {
            float s0 = 0.f, s1 = 0.f, s2 = 0.f, s3 = 0.f;
            const float4* w0 = (const float4*)(W_in + (size_t)(n0 + 0) * IN_DIM);
            const float4* w1 = (const float4*)(W_in + (size_t)(n0 + 1) * IN_DIM);
            const float4* w2 = (const float4*)(W_in + (size_t)(n0 + 2) * IN_DIM);
            const float4* w3 = (const float4*)(W_in + (size_t)(n0 + 3) * IN_DIM);
#pragma unroll 8
            for (int k4 = 0; k4 < IN_DIM / 4; ++k4) {
                float4 xv = *((const float4*)&xr[cur][0] + k4);
                float4 a0 = w0[k4], a1 = w1[k4], a2 = w2[k4], a3 = w3[k4];
                s0 += xv.x * a0.x + xv.y * a0.y + xv.z * a0.z + xv.w * a0.w;
                s1 += xv.x * a1.x + xv.y * a1.y + xv.z * a1.z + xv.w * a1.w;
                s2 += xv.x * a2.x + xv.y * a2.y + xv.z * a2.z + xv.w * a2.w;
                s3 += xv.x * a3.x + xv.y * a3.y + xv.z * a3.z + xv.w * a3.w;
            }
            Icur = make_float4(s0, s1, s2, s3);
        }

#pragma unroll
        for (int c = 0; c < 4; ++c) psc[c] *= a_syn;
        if (prev_any && active) {
#pragma unroll 1
            for (int w = 0; w < 16; ++w) {
                ull_t m = smask[nxt][w];
                while (m) {
                    int bit = __ffsll(m) - 1;
                    m &= m - 1;
                    int npre = ((w >> 2) << 8) + (bit << 2) + (w & 3);
                    const float4 wr = *(const float4*)(W_rec + (size_t)npre * N_NEURON + n0);
                    psc[0] += wr.x; psc[1] += wr.y; psc[2] += wr.z; psc[3] += wr.w;
                }
            }
        }

        float Iv[4] = {Icur.x, Icur.y, Icur.z, Icur.w};
        bool sp[4];
#pragma unroll
        for (int c = 0; c < 4; ++c) {
            float It = Iv[c] + psc[c] + Ia[c];
            float vn = VR + a_v * (v[c] - VR) + one_m_av * It;
            bool s = active && (vn - VTH >= 0.0f);
            float sf = s ? 1.0f : 0.0f;
            vn = vn - (vn - VR) * sf;
            v[c] = vn;
            Ia[c] = aasc[c] * Ia[c] + amp[c] * sf;
            f[c] = (t == 0) ? sf : (a_read * f[c] + one_m_ar * sf);
            if (t >= 199) acc[c] += f[c];
            sp[c] = s;
        }

#pragma unroll
        for (int c = 0; c < 4; ++c) {
            ull_t m = __ballot(sp[c]);
            if (lane == 0) smask[cur][wave * 4 + c] = m;
        }
        int myany = (sp[0] | sp[1] | sp[2] | sp[3]) ? 1 : 0;
        prev_any = __syncthreads_or(myany);
    }

    if (active) {
        acc_sh[n0 + 0] = acc[0]; acc_sh[n0 + 1] = acc[1];
        acc_sh[n0 + 2] = acc[2]; acc_sh[n0 + 3] = acc[3];
    }
    __syncthreads();

    const float inv_cnt = 1.0f / 801.0f;
#pragma unroll
    for (int oo = 0; oo < 5; ++oo) {
        int o = wave * 5 + oo;
        float p = 0.f;
        for (int n = lane; n < N_NEURON; n += 64)
            p += acc_sh[n] * W_out[(size_t)o * N_NEURON + n];
#pragma unroll
        for (int off = 32; off > 0; off >>= 1)
            p += __shfl_down(p, off, 64);
        if (lane == 0)
            out[b * OUT_DIM + o] = out_scale * (p * inv_cnt) + b_out[o];
    }
}

// ============================================================================
extern "C" void kernel_launch(void* const* d_in, const int* in_sizes, int n_in,
                              void* d_out, int out_size, void* d_ws, size_t ws_size,
                              hipStream_t stream)
{
    const float* x         = (const float*)d_in[0];
    const float* W_in      = (const float*)d_in[1];
    const float* W_rec     = (const float*)d_in[2];
    const float* asc_amps  = (const float*)d_in[3];
    const float* k_decay   = (const float*)d_in[4];
    const float* W_out     = (const float*)d_in[5];
    const float* b_out     = (const float*)d_in[6];
    const float* in_scale  = (const float*)d_in[7];
    const float* out_scale = (const float*)d_in[8];
    float* out = (float*)d_out;

    if (ws_size >= WS_NEED) {
        float*    gmaxa = (float*)((char*)d_ws + OFF_GMAXA);
        ushort_t* Wb    = (ushort_t*)((char*)d_ws + OFF_WB);
        wconv_kernel<<<64, 256, 0, stream>>>(W_in, Wb);
        maxgemm_kernel<<<500, 512, 0, stream>>>(x, Wb, in_scale, gmaxa);
        rsnn_seq_kernel<<<BATCH, 256, 0, stream>>>(
            gmaxa, x, W_in, W_rec, asc_amps, k_decay, W_out, b_out,
            in_scale, out_scale, out);
    } else {
        rsnn_seq_kernel<<<BATCH, 256, 0, stream>>>(
            nullptr, x, W_in, W_rec, asc_amps, k_decay, W_out, b_out,
            in_scale, out_scale, out);
    }
}